// Round 2
// baseline (72.008 us; speedup 1.0000x reference)
//
#include <hip/hip_runtime.h>
#include <hip/hip_bf16.h>

#define B_ROWS 8192
#define E_DIM  1024
#define MARGIN 0.2f

typedef __bf16 bf16x8 __attribute__((ext_vector_type(8)));
typedef float  f32x4  __attribute__((ext_vector_type(4)));

__device__ __forceinline__ void gload_lds16(const void* g, void* l) {
    __builtin_amdgcn_global_load_lds(
        (__attribute__((address_space(1))) void*)(g),
        (__attribute__((address_space(3))) void*)(l),
        16, 0, 0);
}

// Wt[n][e] = bf16(W[e][n]) -- GEMM B-operand contiguous along K(=e)
__global__ void transpose_w(const float* __restrict__ W, __bf16* __restrict__ Wt) {
    __shared__ __bf16 tile[32][33];
    int tx = threadIdx.x, ty = threadIdx.y;
    int bx = blockIdx.x * 32;   // n base
    int by = blockIdx.y * 32;   // e base
    tile[ty][tx] = (__bf16)W[(size_t)(by + ty) * E_DIM + bx + tx];
    __syncthreads();
    Wt[(size_t)(bx + ty) * E_DIM + by + tx] = tile[tx][ty];
}

// Fused: A = c = 0.4*m + 0.6*tr_m staged on the fly (regs->bf16->LDS),
// B = Wt via global_load_lds, 2-phase double-buffered pipeline,
// epilogue: rowwise dot with (A_is - A_em), atomicAdd into delta[].
// Block tile 64 rows x 128 cols, BK=32, 4 waves (each 64 x 32 cols).
__global__ __launch_bounds__(256, 4)
void gemm_fused(const float* __restrict__ mIn, const float* __restrict__ trmIn,
                const __bf16* __restrict__ Wt,
                const float* __restrict__ Ais, const float* __restrict__ Aem,
                float* __restrict__ delta) {
    __shared__ __bf16 As[2][64 * 32];    // 2 x 4 KiB
    __shared__ __bf16 Bs[2][128 * 32];   // 2 x 8 KiB

    const int tid  = threadIdx.x;
    const int lane = tid & 63;
    const int wave = tid >> 6;
    const int lr   = lane & 15;
    const int hi   = lane >> 4;

    // Bijective XCD swizzle: 1024 blocks = 8 xcd * (16 panels * 8 colblocks).
    // All 8 col-blocks of a row-panel land on the same XCD -> m/tr_m re-reads hit L2.
    const int bid   = blockIdx.x;
    const int panel = (bid & 7) * 16 + ((bid >> 3) >> 3);
    const int colb  = (bid >> 3) & 7;
    const int rb = panel * 64;
    const int cb = colb * 128;

    // A staging geometry: thread t covers row=t>>2, k-chunk=(t&3)*8 (8 floats)
    const int arow = tid >> 2;
    const int akof = (tid & 3) * 8;
    const float* pm = mIn   + (size_t)(rb + arow) * E_DIM + akof;
    const float* pt = trmIn + (size_t)(rb + arow) * E_DIM + akof;

    auto issueB = [&](int buf, int k0) {
#pragma unroll
        for (int i = 0; i < 2; ++i) {
            int o   = i * 4096 + wave * 1024 + lane * 16;  // byte in 8 KiB tile
            int col = o >> 6;                              // 64 B per 32-bf16 row
            int kb  = o & 63;
            gload_lds16((const char*)Wt + ((size_t)(cb + col) * E_DIM + k0) * 2 + kb,
                        (char*)(&Bs[buf][0]) + i * 4096 + wave * 1024);
        }
    };

    auto writeA = [&](int buf, const float4& m0, const float4& m1,
                      const float4& t0, const float4& t1) {
        bf16x8 v;
        v[0] = (__bf16)(0.4f * m0.x + 0.6f * t0.x);
        v[1] = (__bf16)(0.4f * m0.y + 0.6f * t0.y);
        v[2] = (__bf16)(0.4f * m0.z + 0.6f * t0.z);
        v[3] = (__bf16)(0.4f * m0.w + 0.6f * t0.w);
        v[4] = (__bf16)(0.4f * m1.x + 0.6f * t1.x);
        v[5] = (__bf16)(0.4f * m1.y + 0.6f * t1.y);
        v[6] = (__bf16)(0.4f * m1.z + 0.6f * t1.z);
        v[7] = (__bf16)(0.4f * m1.w + 0.6f * t1.w);
        *(bf16x8*)(&As[buf][tid * 8]) = v;
    };

    f32x4 acc[4][2] = {};

    // ---- prologue: stage k=0 into buf0
    {
        float4 m0 = *(const float4*)(pm);
        float4 m1 = *(const float4*)(pm + 4);
        float4 t0 = *(const float4*)(pt);
        float4 t1 = *(const float4*)(pt + 4);
        issueB(0, 0);
        writeA(0, m0, m1, t0, t1);
    }
    __syncthreads();

    // ---- main loop: 2-phase, prefetch t+1 while computing t
    int cur = 0;
    for (int t = 0; t < 31; ++t) {
        const int k0n = (t + 1) * 32;
        const int nxt = cur ^ 1;

        // issue next-tile loads FIRST (in flight across the MFMA phase)
        float4 m0 = *(const float4*)(pm + k0n);
        float4 m1 = *(const float4*)(pm + k0n + 4);
        float4 t0 = *(const float4*)(pt + k0n);
        float4 t1 = *(const float4*)(pt + k0n + 4);
        issueB(nxt, k0n);

        // compute current tile
        bf16x8 a[4], b[2];
#pragma unroll
        for (int mi = 0; mi < 4; ++mi)
            a[mi] = *(const bf16x8*)(&As[cur][(mi * 16 + lr) * 32 + hi * 8]);
#pragma unroll
        for (int ni = 0; ni < 2; ++ni)
            b[ni] = *(const bf16x8*)(&Bs[cur][(wave * 32 + ni * 16 + lr) * 32 + hi * 8]);
#pragma unroll
        for (int mi = 0; mi < 4; ++mi)
#pragma unroll
            for (int ni = 0; ni < 2; ++ni)
                acc[mi][ni] = __builtin_amdgcn_mfma_f32_16x16x32_bf16(
                    a[mi], b[ni], acc[mi][ni], 0, 0, 0);

        // land next A tile (waits its loads), then one barrier per K-step
        writeA(nxt, m0, m1, t0, t1);
        __syncthreads();
        cur = nxt;
    }

    // ---- final K-step (no prefetch)
    {
        bf16x8 a[4], b[2];
#pragma unroll
        for (int mi = 0; mi < 4; ++mi)
            a[mi] = *(const bf16x8*)(&As[cur][(mi * 16 + lr) * 32 + hi * 8]);
#pragma unroll
        for (int ni = 0; ni < 2; ++ni)
            b[ni] = *(const bf16x8*)(&Bs[cur][(wave * 32 + ni * 16 + lr) * 32 + hi * 8]);
#pragma unroll
        for (int mi = 0; mi < 4; ++mi)
#pragma unroll
            for (int ni = 0; ni < 2; ++ni)
                acc[mi][ni] = __builtin_amdgcn_mfma_f32_16x16x32_bf16(
                    a[mi], b[ni], acc[mi][ni], 0, 0, 0);
    }

    // ---- epilogue: delta[r] += sum_col u[r][col] * (Ais - Aem)[r][col]
    // C/D layout: col = lane&15, row = (lane>>4)*4 + reg
    const int colbase = cb + wave * 32 + lr;
#pragma unroll
    for (int mi = 0; mi < 4; ++mi) {
#pragma unroll
        for (int j = 0; j < 4; ++j) {
            int r = rb + mi * 16 + hi * 4 + j;
            float v = 0.f;
#pragma unroll
            for (int ni = 0; ni < 2; ++ni) {
                size_t idx = (size_t)r * E_DIM + colbase + ni * 16;
                v += acc[mi][ni][j] * (Ais[idx] - Aem[idx]);
            }
            v += __shfl_xor(v, 1);
            v += __shfl_xor(v, 2);
            v += __shfl_xor(v, 4);
            v += __shfl_xor(v, 8);
            if (lr == 0) atomicAdd(&delta[r], v);
        }
    }
}

__global__ void hinge_sum(const float* __restrict__ delta, float* __restrict__ out) {
    float s = 0.f;
    for (int i = threadIdx.x; i < B_ROWS; i += 256)
        s += fmaxf(MARGIN + delta[i], 0.f);
#pragma unroll
    for (int off = 32; off > 0; off >>= 1) s += __shfl_down(s, off);
    __shared__ float wsum[4];
    int lane = threadIdx.x & 63, w = threadIdx.x >> 6;
    if (lane == 0) wsum[w] = s;
    __syncthreads();
    if (threadIdx.x == 0) out[0] = wsum[0] + wsum[1] + wsum[2] + wsum[3];
}

extern "C" void kernel_launch(void* const* d_in, const int* in_sizes, int n_in,
                              void* d_out, int out_size, void* d_ws, size_t ws_size,
                              hipStream_t stream) {
    const float* A_is = (const float*)d_in[0];
    const float* A_em = (const float*)d_in[1];
    const float* m    = (const float*)d_in[2];
    const float* tr_m = (const float*)d_in[3];
    const float* W    = (const float*)d_in[4];
    // d_in[5] = b : cancels in diag_is - diag_em, unused.
    float* out = (float*)d_out;

    char* ws = (char*)d_ws;
    __bf16* wt   = (__bf16*)ws;                              // 2 MiB
    float*  delta = (float*)(ws + (size_t)2 * 1024 * 1024);  // 32 KiB

    hipMemsetAsync(delta, 0, B_ROWS * sizeof(float), stream);
    transpose_w<<<dim3(32, 32), dim3(32, 32), 0, stream>>>(W, wt);
    gemm_fused<<<1024, 256, 0, stream>>>(m, tr_m, wt, A_is, A_em, delta);
    hinge_sum<<<1, 256, 0, stream>>>(delta, out);
}